// Round 1
// baseline (1264.491 us; speedup 1.0000x reference)
//
#include <hip/hip_runtime.h>
#include <hip/hip_bf16.h>

// GNNClassifier: 3x SAGEConv(mean) + ReLU -> global_mean_pool -> Linear+ReLU -> Linear
// N=50000 nodes, E=800000 edges, IN=128, HID=256, OUT=10, G=64 graphs. All fp32.
//
// Strategy R1 (correct fp32 baseline):
//  - Build CSR by dst once per call (hist + shuffle-scan + atomic placement) so
//    feature aggregation is gather-based (no fp32 atomics, coalesced 1KiB/edge).
//  - Fused dual-GEMM per layer: h' = relu(agg @ Wl^T + b + h @ Wr^T),
//    128x128 tile, 8x8 microtile (split 2x2 of 4x4 to keep LDS reads 2-way max),
//    BK=8, fp32 vector ALU.
//  - Segmented pool (batch is sorted) with few atomics, tiny fused MLP.

#define NN_CONST 50000
#define HID 256

// ---------------------------------------------------------------- CSR build
__global__ void count_deg_kernel(const int* __restrict__ dst, int* __restrict__ hist, int E) {
    int i = blockIdx.x * blockDim.x + threadIdx.x;
    if (i < E) atomicAdd(&hist[dst[i]], 1);
}

// single-block exclusive scan (shuffle-based), writes offsets[0..n] and cursor[i]=offsets[i]
__global__ void scan_kernel(int* __restrict__ hist_cursor, int* __restrict__ offsets, int nn) {
    __shared__ int wtot[16];
    const int tid = threadIdx.x;            // 1024 threads
    const int lane = tid & 63, wid = tid >> 6;
    int running = 0;
    for (int base = 0; base < nn; base += 1024) {
        int i = base + tid;
        int v = (i < nn) ? hist_cursor[i] : 0;
        int incl = v;
        #pragma unroll
        for (int d = 1; d < 64; d <<= 1) {
            int t = __shfl_up(incl, d, 64);
            if (lane >= d) incl += t;
        }
        if (lane == 63) wtot[wid] = incl;
        __syncthreads();
        int wbase = 0, total = 0;
        #pragma unroll
        for (int w = 0; w < 16; ++w) {
            int t = wtot[w];
            if (w < wid) wbase += t;
            total += t;
        }
        if (i < nn) {
            int o = running + wbase + (incl - v);
            offsets[i] = o;
            hist_cursor[i] = o;   // cursor copy for placement pass
        }
        running += total;
        __syncthreads();
    }
    if (tid == 0) offsets[nn] = running;
}

__global__ void fill_csr_kernel(const int* __restrict__ src, const int* __restrict__ dst,
                                int* __restrict__ cursor, int* __restrict__ csr, int E) {
    int i = blockIdx.x * blockDim.x + threadIdx.x;
    if (i < E) {
        int p = atomicAdd(&cursor[dst[i]], 1);
        csr[p] = src[i];
    }
}

// ---------------------------------------------------------------- aggregation
// mean over incoming edges; C channels, C/4 threads per node (float4 lanes)
template <int C>
__global__ __launch_bounds__(256)
void agg_kernel(const float* __restrict__ h, const int* __restrict__ offsets,
                const int* __restrict__ csr, float* __restrict__ out, int nn) {
    constexpr int TPN = C / 4;          // threads per node
    constexpr int NPB = 256 / TPN;      // nodes per block
    const int node = blockIdx.x * NPB + (int)(threadIdx.x / TPN);
    const int lane = threadIdx.x % TPN;
    if (node >= nn) return;
    const int e0 = offsets[node], e1 = offsets[node + 1];
    float4 acc = make_float4(0.f, 0.f, 0.f, 0.f);
    for (int e = e0; e < e1; ++e) {
        const int s = csr[e];
        const float4 v = *(const float4*)(h + (size_t)s * C + lane * 4);
        acc.x += v.x; acc.y += v.y; acc.z += v.z; acc.w += v.w;
    }
    const float inv = 1.0f / fmaxf((float)(e1 - e0), 1.0f);
    float4 r;
    r.x = acc.x * inv; r.y = acc.y * inv; r.z = acc.z * inv; r.w = acc.w * inv;
    *(float4*)(out + (size_t)node * C + lane * 4) = r;
}

// ---------------------------------------------------------------- fused dual GEMM
// C[M,256] = relu(A1 @ W1^T + A2 @ W2^T + bias). W row-major [256, K].
// 128x128 tile, 256 threads, 8x8 microtile as 2x2 blocks of 4x4, BK=8.
template <int K>
__global__ __launch_bounds__(256)
void gemm2_bias_relu(const float* __restrict__ A1, const float* __restrict__ A2,
                     const float* __restrict__ W1, const float* __restrict__ W2,
                     const float* __restrict__ bias, float* __restrict__ Cout, int M) {
    constexpr int N = 256;
    __shared__ float As[8][128];
    __shared__ float Bs[8][128];
    const int tid = threadIdx.x;
    const int tx = tid & 15, ty = tid >> 4;
    const int row0 = blockIdx.x * 128, col0 = blockIdx.y * 128;
    const int lr = tid >> 1;            // 0..127 tile row / weight row
    const int lc = (tid & 1) * 4;       // 0 or 4 within BK

    float acc[2][2][4][4];
    #pragma unroll
    for (int a = 0; a < 2; ++a)
        #pragma unroll
        for (int b = 0; b < 2; ++b)
            #pragma unroll
            for (int i = 0; i < 4; ++i)
                #pragma unroll
                for (int j = 0; j < 4; ++j) acc[a][b][i][j] = 0.f;

    #pragma unroll
    for (int phase = 0; phase < 2; ++phase) {
        const float* __restrict__ A = phase ? A2 : A1;
        const float* __restrict__ W = phase ? W2 : W1;
        for (int kt = 0; kt < K; kt += 8) {
            int ar = row0 + lr; if (ar >= M) ar = M - 1;   // clamp (stores guarded)
            const float4 a4 = *(const float4*)(A + (size_t)ar * K + kt + lc);
            const float4 b4 = *(const float4*)(W + (size_t)(col0 + lr) * K + kt + lc);
            __syncthreads();   // previous tile fully consumed
            As[lc + 0][lr] = a4.x; As[lc + 1][lr] = a4.y;
            As[lc + 2][lr] = a4.z; As[lc + 3][lr] = a4.w;
            Bs[lc + 0][lr] = b4.x; Bs[lc + 1][lr] = b4.y;
            Bs[lc + 2][lr] = b4.z; Bs[lc + 3][lr] = b4.w;
            __syncthreads();
            #pragma unroll
            for (int k = 0; k < 8; ++k) {
                const float4 a0 = *(const float4*)&As[k][ty * 4];
                const float4 a1 = *(const float4*)&As[k][64 + ty * 4];
                const float4 b0 = *(const float4*)&Bs[k][tx * 4];
                const float4 b1 = *(const float4*)&Bs[k][64 + tx * 4];
                const float av[2][4] = {{a0.x, a0.y, a0.z, a0.w}, {a1.x, a1.y, a1.z, a1.w}};
                const float bv[2][4] = {{b0.x, b0.y, b0.z, b0.w}, {b1.x, b1.y, b1.z, b1.w}};
                #pragma unroll
                for (int ih = 0; ih < 2; ++ih)
                    #pragma unroll
                    for (int i = 0; i < 4; ++i)
                        #pragma unroll
                        for (int jh = 0; jh < 2; ++jh)
                            #pragma unroll
                            for (int j = 0; j < 4; ++j)
                                acc[ih][jh][i][j] = fmaf(av[ih][i], bv[jh][j], acc[ih][jh][i][j]);
            }
        }
    }

    #pragma unroll
    for (int ih = 0; ih < 2; ++ih)
        #pragma unroll
        for (int i = 0; i < 4; ++i) {
            const int r = row0 + ih * 64 + ty * 4 + i;
            if (r < M) {
                #pragma unroll
                for (int jh = 0; jh < 2; ++jh) {
                    const int c = col0 + jh * 64 + tx * 4;
                    float4 o;
                    o.x = fmaxf(acc[ih][jh][i][0] + bias[c + 0], 0.f);
                    o.y = fmaxf(acc[ih][jh][i][1] + bias[c + 1], 0.f);
                    o.z = fmaxf(acc[ih][jh][i][2] + bias[c + 2], 0.f);
                    o.w = fmaxf(acc[ih][jh][i][3] + bias[c + 3], 0.f);
                    *(float4*)(Cout + (size_t)r * N + c) = o;
                }
            }
        }
}

// ---------------------------------------------------------------- pooling
__global__ void count_nodes_kernel(const int* __restrict__ batch, int* __restrict__ counts, int nn) {
    int i = blockIdx.x * blockDim.x + threadIdx.x;
    if (i < nn) atomicAdd(&counts[batch[i]], 1);
}

// batch is sorted: each block sums a 64-node chunk per-channel, flushes on graph change
__global__ __launch_bounds__(256)
void pool_kernel(const float* __restrict__ h, const int* __restrict__ batch,
                 float* __restrict__ pooled, int nn) {
    const int c = threadIdx.x;          // 256 channels
    const int n0 = blockIdx.x * 64;
    const int n1 = min(n0 + 64, nn);
    if (n0 >= nn) return;
    float acc = 0.f;
    int cur = batch[n0];
    for (int n = n0; n < n1; ++n) {
        const int g = batch[n];
        if (g != cur) {
            atomicAdd(&pooled[cur * 256 + c], acc);
            acc = 0.f; cur = g;
        }
        acc += h[(size_t)n * 256 + c];
    }
    atomicAdd(&pooled[cur * 256 + c], acc);
}

// per-graph MLP: g = relu((pooled/cnt) @ lin1W^T + b1); out = g @ lin2W^T + b2
__global__ __launch_bounds__(128)
void mlp_kernel(const float* __restrict__ pooled, const int* __restrict__ counts,
                const float* __restrict__ lin1W, const float* __restrict__ lin1b,
                const float* __restrict__ lin2W, const float* __restrict__ lin2b,
                float* __restrict__ out) {
    __shared__ float g1[128];
    const int g = blockIdx.x;
    const int j = threadIdx.x;          // 128
    const float inv = 1.0f / fmaxf((float)counts[g], 1.0f);
    float acc = lin1b[j];
    #pragma unroll 4
    for (int k = 0; k < 256; ++k)
        acc = fmaf(pooled[g * 256 + k] * inv, lin1W[j * 256 + k], acc);
    g1[j] = fmaxf(acc, 0.f);
    __syncthreads();
    if (j < 10) {
        float o = lin2b[j];
        #pragma unroll 4
        for (int k = 0; k < 128; ++k)
            o = fmaf(g1[k], lin2W[j * 128 + k], o);
        out[g * 10 + j] = o;
    }
}

// ---------------------------------------------------------------- launcher
extern "C" void kernel_launch(void* const* d_in, const int* in_sizes, int n_in,
                              void* d_out, int out_size, void* d_ws, size_t ws_size,
                              hipStream_t stream) {
    const float* x     = (const float*)d_in[0];
    const int*   eidx  = (const int*)d_in[1];
    const int*   batch = (const int*)d_in[2];
    const float* W1l = (const float*)d_in[3];
    const float* b1  = (const float*)d_in[4];
    const float* W1r = (const float*)d_in[5];
    const float* W2l = (const float*)d_in[6];
    const float* b2  = (const float*)d_in[7];
    const float* W2r = (const float*)d_in[8];
    const float* W3l = (const float*)d_in[9];
    const float* b3  = (const float*)d_in[10];
    const float* W3r = (const float*)d_in[11];
    const float* lin1W = (const float*)d_in[12];
    const float* lin1b = (const float*)d_in[13];
    const float* lin2W = (const float*)d_in[14];
    const float* lin2b = (const float*)d_in[15];
    float* out = (float*)d_out;

    const int E  = in_sizes[1] / 2;
    const int NN = in_sizes[2];
    const int* src = eidx;
    const int* dst = eidx + E;

    // workspace layout (16B aligned chunks)
    char* ws = (char*)d_ws;
    size_t off = 0;
    float* agg = (float*)(ws + off); off += (size_t)NN * HID * 4;        // 51.2 MB (layer1 uses 25.6)
    float* hA  = (float*)(ws + off); off += (size_t)NN * HID * 4;
    float* hB  = (float*)(ws + off); off += (size_t)NN * HID * 4;
    int* offsets = (int*)(ws + off); off += ((size_t)(NN + 1) * 4 + 255) / 256 * 256;
    int* cursor  = (int*)(ws + off); off += ((size_t)NN * 4 + 255) / 256 * 256;   // hist, then cursor
    int* csr     = (int*)(ws + off); off += ((size_t)E * 4 + 255) / 256 * 256;
    float* pooled = (float*)(ws + off); off += 64 * 256 * 4;
    int* counts   = (int*)(ws + off); off += 256;
    (void)ws_size; (void)n_in; (void)out_size;

    const int TB = 256;
    const int egrid = (E + TB - 1) / TB;
    const int mgrid = (NN + 127) / 128;

    // --- CSR build (per call; ws is re-poisoned every launch) ---
    hipMemsetAsync(cursor, 0, (size_t)NN * 4, stream);
    count_deg_kernel<<<egrid, TB, 0, stream>>>(dst, cursor, E);
    scan_kernel<<<1, 1024, 0, stream>>>(cursor, offsets, NN);
    fill_csr_kernel<<<egrid, TB, 0, stream>>>(src, dst, cursor, csr, E);

    // --- layer 1 (IN=128) ---
    agg_kernel<128><<<(NN + 7) / 8, TB, 0, stream>>>(x, offsets, csr, agg, NN);
    gemm2_bias_relu<128><<<dim3(mgrid, 2), TB, 0, stream>>>(agg, x, W1l, W1r, b1, hA, NN);
    // --- layer 2 ---
    agg_kernel<256><<<(NN + 3) / 4, TB, 0, stream>>>(hA, offsets, csr, agg, NN);
    gemm2_bias_relu<256><<<dim3(mgrid, 2), TB, 0, stream>>>(agg, hA, W2l, W2r, b2, hB, NN);
    // --- layer 3 ---
    agg_kernel<256><<<(NN + 3) / 4, TB, 0, stream>>>(hB, offsets, csr, agg, NN);
    gemm2_bias_relu<256><<<dim3(mgrid, 2), TB, 0, stream>>>(agg, hB, W3l, W3r, b3, hA, NN);

    // --- pool + MLP ---
    hipMemsetAsync(pooled, 0, 64 * 256 * 4 + 256, stream);   // pooled + counts (contiguous)
    count_nodes_kernel<<<(NN + TB - 1) / TB, TB, 0, stream>>>(batch, counts, NN);
    pool_kernel<<<(NN + 63) / 64, TB, 0, stream>>>(hA, batch, pooled, NN);
    mlp_kernel<<<64, 128, 0, stream>>>(pooled, counts, lin1W, lin1b, lin2W, lin2b, out);
}

// Round 2
// 986.933 us; speedup vs baseline: 1.2812x; 1.2812x over previous
//
#include <hip/hip_runtime.h>
#include <hip/hip_bf16.h>

// GNNClassifier: 3x SAGEConv(mean) + ReLU -> global_mean_pool -> Linear+ReLU -> Linear
// N=50000 nodes, E=800000 edges, IN=128, HID=256, OUT=10, G=64 graphs. All fp32.
//
// R2: fix helper kernels found in R1 profile.
//  - scan: single-block serial scan (40ms under profiling) -> 3-kernel multi-block scan.
//  - count_nodes: 50K atomics on 64 counters (234us) -> per-block LDS histogram (~3us).
//  - GEMM / agg / pool unchanged (profile them properly this round).

#define HID 256

// ---------------------------------------------------------------- CSR build
__global__ void count_deg_kernel(const int* __restrict__ dst, int* __restrict__ hist, int E) {
    int i = blockIdx.x * blockDim.x + threadIdx.x;
    if (i < E) atomicAdd(&hist[dst[i]], 1);
}

// Multi-block exclusive scan, step A: each block scans 1024 elems (256 thr x 4),
// writes per-element exclusive-within-block prefix + block total.
__global__ __launch_bounds__(256)
void scanA_kernel(const int* __restrict__ hist, int* __restrict__ excl,
                  int* __restrict__ blocksums, int nn) {
    const int tid = threadIdx.x, lane = tid & 63, wid = tid >> 6;
    const int i0 = blockIdx.x * 1024 + tid * 4;
    int v0 = (i0 + 0 < nn) ? hist[i0 + 0] : 0;
    int v1 = (i0 + 1 < nn) ? hist[i0 + 1] : 0;
    int v2 = (i0 + 2 < nn) ? hist[i0 + 2] : 0;
    int v3 = (i0 + 3 < nn) ? hist[i0 + 3] : 0;
    const int s = v0 + v1 + v2 + v3;
    int incl = s;
    #pragma unroll
    for (int d = 1; d < 64; d <<= 1) {
        int t = __shfl_up(incl, d, 64);
        if (lane >= d) incl += t;
    }
    __shared__ int wt[4];
    if (lane == 63) wt[wid] = incl;
    __syncthreads();
    int wbase = 0, total = 0;
    #pragma unroll
    for (int w = 0; w < 4; ++w) {
        int t = wt[w];
        if (w < wid) wbase += t;
        total += t;
    }
    int e = wbase + (incl - s);   // exclusive prefix of this thread's 4-chunk
    if (i0 + 0 < nn) excl[i0 + 0] = e;           e += v0;
    if (i0 + 1 < nn) excl[i0 + 1] = e;           e += v1;
    if (i0 + 2 < nn) excl[i0 + 2] = e;           e += v2;
    if (i0 + 3 < nn) excl[i0 + 3] = e;
    if (tid == 0) blocksums[blockIdx.x] = total;
}

// step B: one wave exclusive-scans the block sums (nb <= 64) and writes offsets[nn]=E.
__global__ void scanB_kernel(int* __restrict__ blocksums, int* __restrict__ offsets,
                             int nb, int nn, int E) {
    const int lane = threadIdx.x;   // 64
    int v = (lane < nb) ? blocksums[lane] : 0;
    int incl = v;
    #pragma unroll
    for (int d = 1; d < 64; d <<= 1) {
        int t = __shfl_up(incl, d, 64);
        if (lane >= d) incl += t;
    }
    if (lane < nb) blocksums[lane] = incl - v;   // exclusive
    if (lane == 0) offsets[nn] = E;
}

// step C: add block base; also initialize cursor=offsets for the fill pass.
__global__ __launch_bounds__(256)
void scanC_kernel(int* __restrict__ offsets, int* __restrict__ cursor,
                  const int* __restrict__ blocksums, int nn) {
    const int i0 = blockIdx.x * 1024 + threadIdx.x * 4;
    const int base = blocksums[blockIdx.x];
    #pragma unroll
    for (int j = 0; j < 4; ++j) {
        const int i = i0 + j;
        if (i < nn) {
            const int o = offsets[i] + base;
            offsets[i] = o;
            cursor[i] = o;
        }
    }
}

__global__ void fill_csr_kernel(const int* __restrict__ src, const int* __restrict__ dst,
                                int* __restrict__ cursor, int* __restrict__ csr, int E) {
    int i = blockIdx.x * blockDim.x + threadIdx.x;
    if (i < E) {
        int p = atomicAdd(&cursor[dst[i]], 1);
        csr[p] = src[i];
    }
}

// ---------------------------------------------------------------- aggregation
// mean over incoming edges; C channels, C/4 threads per node (float4 lanes)
template <int C>
__global__ __launch_bounds__(256)
void agg_kernel(const float* __restrict__ h, const int* __restrict__ offsets,
                const int* __restrict__ csr, float* __restrict__ out, int nn) {
    constexpr int TPN = C / 4;          // threads per node
    constexpr int NPB = 256 / TPN;      // nodes per block
    const int node = blockIdx.x * NPB + (int)(threadIdx.x / TPN);
    const int lane = threadIdx.x % TPN;
    if (node >= nn) return;
    const int e0 = offsets[node], e1 = offsets[node + 1];
    float4 acc = make_float4(0.f, 0.f, 0.f, 0.f);
    for (int e = e0; e < e1; ++e) {
        const int s = csr[e];
        const float4 v = *(const float4*)(h + (size_t)s * C + lane * 4);
        acc.x += v.x; acc.y += v.y; acc.z += v.z; acc.w += v.w;
    }
    const float inv = 1.0f / fmaxf((float)(e1 - e0), 1.0f);
    float4 r;
    r.x = acc.x * inv; r.y = acc.y * inv; r.z = acc.z * inv; r.w = acc.w * inv;
    *(float4*)(out + (size_t)node * C + lane * 4) = r;
}

// ---------------------------------------------------------------- fused dual GEMM
// C[M,256] = relu(A1 @ W1^T + A2 @ W2^T + bias). W row-major [256, K].
// 128x128 tile, 256 threads, 8x8 microtile as 2x2 blocks of 4x4, BK=8.
template <int K>
__global__ __launch_bounds__(256)
void gemm2_bias_relu(const float* __restrict__ A1, const float* __restrict__ A2,
                     const float* __restrict__ W1, const float* __restrict__ W2,
                     const float* __restrict__ bias, float* __restrict__ Cout, int M) {
    constexpr int N = 256;
    __shared__ float As[8][128];
    __shared__ float Bs[8][128];
    const int tid = threadIdx.x;
    const int tx = tid & 15, ty = tid >> 4;
    const int row0 = blockIdx.x * 128, col0 = blockIdx.y * 128;
    const int lr = tid >> 1;            // 0..127 tile row / weight row
    const int lc = (tid & 1) * 4;       // 0 or 4 within BK

    float acc[2][2][4][4];
    #pragma unroll
    for (int a = 0; a < 2; ++a)
        #pragma unroll
        for (int b = 0; b < 2; ++b)
            #pragma unroll
            for (int i = 0; i < 4; ++i)
                #pragma unroll
                for (int j = 0; j < 4; ++j) acc[a][b][i][j] = 0.f;

    #pragma unroll
    for (int phase = 0; phase < 2; ++phase) {
        const float* __restrict__ A = phase ? A2 : A1;
        const float* __restrict__ W = phase ? W2 : W1;
        for (int kt = 0; kt < K; kt += 8) {
            int ar = row0 + lr; if (ar >= M) ar = M - 1;   // clamp (stores guarded)
            const float4 a4 = *(const float4*)(A + (size_t)ar * K + kt + lc);
            const float4 b4 = *(const float4*)(W + (size_t)(col0 + lr) * K + kt + lc);
            __syncthreads();   // previous tile fully consumed
            As[lc + 0][lr] = a4.x; As[lc + 1][lr] = a4.y;
            As[lc + 2][lr] = a4.z; As[lc + 3][lr] = a4.w;
            Bs[lc + 0][lr] = b4.x; Bs[lc + 1][lr] = b4.y;
            Bs[lc + 2][lr] = b4.z; Bs[lc + 3][lr] = b4.w;
            __syncthreads();
            #pragma unroll
            for (int k = 0; k < 8; ++k) {
                const float4 a0 = *(const float4*)&As[k][ty * 4];
                const float4 a1 = *(const float4*)&As[k][64 + ty * 4];
                const float4 b0 = *(const float4*)&Bs[k][tx * 4];
                const float4 b1 = *(const float4*)&Bs[k][64 + tx * 4];
                const float av[2][4] = {{a0.x, a0.y, a0.z, a0.w}, {a1.x, a1.y, a1.z, a1.w}};
                const float bv[2][4] = {{b0.x, b0.y, b0.z, b0.w}, {b1.x, b1.y, b1.z, b1.w}};
                #pragma unroll
                for (int ih = 0; ih < 2; ++ih)
                    #pragma unroll
                    for (int i = 0; i < 4; ++i)
                        #pragma unroll
                        for (int jh = 0; jh < 2; ++jh)
                            #pragma unroll
                            for (int j = 0; j < 4; ++j)
                                acc[ih][jh][i][j] = fmaf(av[ih][i], bv[jh][j], acc[ih][jh][i][j]);
            }
        }
    }

    #pragma unroll
    for (int ih = 0; ih < 2; ++ih)
        #pragma unroll
        for (int i = 0; i < 4; ++i) {
            const int r = row0 + ih * 64 + ty * 4 + i;
            if (r < M) {
                #pragma unroll
                for (int jh = 0; jh < 2; ++jh) {
                    const int c = col0 + jh * 64 + tx * 4;
                    float4 o;
                    o.x = fmaxf(acc[ih][jh][i][0] + bias[c + 0], 0.f);
                    o.y = fmaxf(acc[ih][jh][i][1] + bias[c + 1], 0.f);
                    o.z = fmaxf(acc[ih][jh][i][2] + bias[c + 2], 0.f);
                    o.w = fmaxf(acc[ih][jh][i][3] + bias[c + 3], 0.f);
                    *(float4*)(Cout + (size_t)r * N + c) = o;
                }
            }
        }
}

// ---------------------------------------------------------------- pooling
// per-block LDS histogram of batch ids (64 graphs) -> few global atomics
__global__ __launch_bounds__(256)
void count_nodes_kernel(const int* __restrict__ batch, int* __restrict__ counts, int nn) {
    __shared__ int h[64];
    const int tid = threadIdx.x;
    if (tid < 64) h[tid] = 0;
    __syncthreads();
    const int i0 = blockIdx.x * 1024 + tid * 4;
    #pragma unroll
    for (int j = 0; j < 4; ++j) {
        const int i = i0 + j;
        if (i < nn) atomicAdd(&h[batch[i]], 1);
    }
    __syncthreads();
    if (tid < 64 && h[tid] != 0) atomicAdd(&counts[tid], h[tid]);
}

// batch is sorted: each block sums a 64-node chunk per-channel, flushes on graph change
__global__ __launch_bounds__(256)
void pool_kernel(const float* __restrict__ h, const int* __restrict__ batch,
                 float* __restrict__ pooled, int nn) {
    const int c = threadIdx.x;          // 256 channels
    const int n0 = blockIdx.x * 64;
    const int n1 = min(n0 + 64, nn);
    if (n0 >= nn) return;
    float acc = 0.f;
    int cur = batch[n0];
    for (int n = n0; n < n1; ++n) {
        const int g = batch[n];
        if (g != cur) {
            atomicAdd(&pooled[cur * 256 + c], acc);
            acc = 0.f; cur = g;
        }
        acc += h[(size_t)n * 256 + c];
    }
    atomicAdd(&pooled[cur * 256 + c], acc);
}

// per-graph MLP: g = relu((pooled/cnt) @ lin1W^T + b1); out = g @ lin2W^T + b2
__global__ __launch_bounds__(128)
void mlp_kernel(const float* __restrict__ pooled, const int* __restrict__ counts,
                const float* __restrict__ lin1W, const float* __restrict__ lin1b,
                const float* __restrict__ lin2W, const float* __restrict__ lin2b,
                float* __restrict__ out) {
    __shared__ float g1[128];
    const int g = blockIdx.x;
    const int j = threadIdx.x;          // 128
    const float inv = 1.0f / fmaxf((float)counts[g], 1.0f);
    float acc = lin1b[j];
    #pragma unroll 4
    for (int k = 0; k < 256; ++k)
        acc = fmaf(pooled[g * 256 + k] * inv, lin1W[j * 256 + k], acc);
    g1[j] = fmaxf(acc, 0.f);
    __syncthreads();
    if (j < 10) {
        float o = lin2b[j];
        #pragma unroll 4
        for (int k = 0; k < 128; ++k)
            o = fmaf(g1[k], lin2W[j * 128 + k], o);
        out[g * 10 + j] = o;
    }
}

// ---------------------------------------------------------------- launcher
extern "C" void kernel_launch(void* const* d_in, const int* in_sizes, int n_in,
                              void* d_out, int out_size, void* d_ws, size_t ws_size,
                              hipStream_t stream) {
    const float* x     = (const float*)d_in[0];
    const int*   eidx  = (const int*)d_in[1];
    const int*   batch = (const int*)d_in[2];
    const float* W1l = (const float*)d_in[3];
    const float* b1  = (const float*)d_in[4];
    const float* W1r = (const float*)d_in[5];
    const float* W2l = (const float*)d_in[6];
    const float* b2  = (const float*)d_in[7];
    const float* W2r = (const float*)d_in[8];
    const float* W3l = (const float*)d_in[9];
    const float* b3  = (const float*)d_in[10];
    const float* W3r = (const float*)d_in[11];
    const float* lin1W = (const float*)d_in[12];
    const float* lin1b = (const float*)d_in[13];
    const float* lin2W = (const float*)d_in[14];
    const float* lin2b = (const float*)d_in[15];
    float* out = (float*)d_out;

    const int E  = in_sizes[1] / 2;
    const int NN = in_sizes[2];
    const int* src = eidx;
    const int* dst = eidx + E;

    // workspace layout (16B aligned chunks)
    char* ws = (char*)d_ws;
    size_t off = 0;
    float* agg = (float*)(ws + off); off += (size_t)NN * HID * 4;
    float* hA  = (float*)(ws + off); off += (size_t)NN * HID * 4;
    float* hB  = (float*)(ws + off); off += (size_t)NN * HID * 4;
    int* offsets = (int*)(ws + off); off += ((size_t)(NN + 1) * 4 + 255) / 256 * 256;
    int* cursor  = (int*)(ws + off); off += ((size_t)NN * 4 + 255) / 256 * 256;   // hist, then cursor
    int* csr     = (int*)(ws + off); off += ((size_t)E * 4 + 255) / 256 * 256;
    int* blocksums = (int*)(ws + off); off += 256;
    float* pooled = (float*)(ws + off); off += 64 * 256 * 4;
    int* counts   = (int*)(ws + off); off += 256;
    (void)ws_size; (void)n_in; (void)out_size;

    const int TB = 256;
    const int egrid = (E + TB - 1) / TB;
    const int mgrid = (NN + 127) / 128;
    const int sgrid = (NN + 1023) / 1024;   // 49 scan blocks (<=64 required by scanB)

    // --- CSR build (per call; ws is re-poisoned every launch) ---
    hipMemsetAsync(cursor, 0, (size_t)NN * 4, stream);
    count_deg_kernel<<<egrid, TB, 0, stream>>>(dst, cursor, E);
    scanA_kernel<<<sgrid, TB, 0, stream>>>(cursor, offsets, blocksums, NN);
    scanB_kernel<<<1, 64, 0, stream>>>(blocksums, offsets, sgrid, NN, E);
    scanC_kernel<<<sgrid, TB, 0, stream>>>(offsets, cursor, blocksums, NN);
    fill_csr_kernel<<<egrid, TB, 0, stream>>>(src, dst, cursor, csr, E);

    // --- layer 1 (IN=128) ---
    agg_kernel<128><<<(NN + 7) / 8, TB, 0, stream>>>(x, offsets, csr, agg, NN);
    gemm2_bias_relu<128><<<dim3(mgrid, 2), TB, 0, stream>>>(agg, x, W1l, W1r, b1, hA, NN);
    // --- layer 2 ---
    agg_kernel<256><<<(NN + 3) / 4, TB, 0, stream>>>(hA, offsets, csr, agg, NN);
    gemm2_bias_relu<256><<<dim3(mgrid, 2), TB, 0, stream>>>(agg, hA, W2l, W2r, b2, hB, NN);
    // --- layer 3 ---
    agg_kernel<256><<<(NN + 3) / 4, TB, 0, stream>>>(hB, offsets, csr, agg, NN);
    gemm2_bias_relu<256><<<dim3(mgrid, 2), TB, 0, stream>>>(agg, hB, W3l, W3r, b3, hA, NN);

    // --- pool + MLP ---
    hipMemsetAsync(pooled, 0, 64 * 256 * 4 + 256, stream);   // pooled + counts (contiguous)
    count_nodes_kernel<<<sgrid, TB, 0, stream>>>(batch, counts, NN);
    pool_kernel<<<(NN + 63) / 64, TB, 0, stream>>>(hA, batch, pooled, NN);
    mlp_kernel<<<64, 128, 0, stream>>>(pooled, counts, lin1W, lin1b, lin2W, lin2b, out);
}

// Round 3
// 485.764 us; speedup vs baseline: 2.6031x; 2.0317x over previous
//
#include <hip/hip_runtime.h>
#include <hip/hip_bf16.h>

// GNNClassifier: 3x SAGEConv(mean) + ReLU -> global_mean_pool -> Linear+ReLU -> Linear
// N=50000 nodes, E=800000 edges, IN=128, HID=256, OUT=10, G=64 graphs.
//
// R3: bf16 MFMA GEMMs (16x16x32), fp32 accumulate; bf16 activations everywhere
// (halves agg gather traffic); fp32 bias/pool/MLP for accuracy headroom.
//  - GEMM: 128x128 tile, 4 waves x (64x64), BK=64, global_load_lds width=16,
//    XOR-swizzled LDS (chunk ^= row&7) -> 2-way max bank aliasing (free).
//  - CSR build + pool/MLP as in R2.

#define HID 256
typedef unsigned short ushort_t;
typedef __bf16 bf16x8 __attribute__((ext_vector_type(8)));
typedef float  f32x4  __attribute__((ext_vector_type(4)));

__device__ __forceinline__ unsigned short f2bf(float f) {
    unsigned int u = __float_as_uint(f);
    unsigned int r = (u + 0x7fffu + ((u >> 16) & 1u)) >> 16;
    return (unsigned short)r;
}
__device__ __forceinline__ float bflo(unsigned int u) { return __uint_as_float(u << 16); }
__device__ __forceinline__ float bfhi(unsigned int u) { return __uint_as_float(u & 0xffff0000u); }
__device__ __forceinline__ unsigned int packbf(float a, float b) {
    return (unsigned int)f2bf(a) | ((unsigned int)f2bf(b) << 16);
}
__device__ __forceinline__ void gld16(const void* g, void* l) {
    __builtin_amdgcn_global_load_lds(
        (const __attribute__((address_space(1))) unsigned int*)g,
        (__attribute__((address_space(3))) unsigned int*)l, 16, 0, 0);
}

// ---------------------------------------------------------------- conversions
__global__ __launch_bounds__(256)
void cvt_x_kernel(const float* __restrict__ x, ushort_t* __restrict__ xb, int n) {
    const int i = (blockIdx.x * 256 + threadIdx.x) * 4;
    if (i < n) {
        const float4 v = *(const float4*)(x + i);
        unsigned int lo = packbf(v.x, v.y), hi = packbf(v.z, v.w);
        *(uint2*)(xb + i) = make_uint2(lo, hi);
    }
}

__global__ __launch_bounds__(256)
void cvt_w_kernel(const float* __restrict__ W1l, const float* __restrict__ W1r,
                  const float* __restrict__ W2l, const float* __restrict__ W2r,
                  const float* __restrict__ W3l, const float* __restrict__ W3r,
                  ushort_t* __restrict__ dst, int s1, int s2) {
    const int i = blockIdx.x * 256 + threadIdx.x;
    const int total = 2 * s1 + 4 * s2;
    if (i >= total) return;
    int off = i;
    const float* src;
    if (off < s1) src = W1l;
    else if ((off -= s1) < s1) src = W1r;
    else if ((off -= s1) < s2) src = W2l;
    else if ((off -= s2) < s2) src = W2r;
    else if ((off -= s2) < s2) src = W3l;
    else { off -= s2; src = W3r; }
    dst[i] = f2bf(src[off]);
}

// ---------------------------------------------------------------- CSR build
__global__ void count_deg_kernel(const int* __restrict__ dst, int* __restrict__ hist, int E) {
    int i = blockIdx.x * blockDim.x + threadIdx.x;
    if (i < E) atomicAdd(&hist[dst[i]], 1);
}

__global__ __launch_bounds__(256)
void scanA_kernel(const int* __restrict__ hist, int* __restrict__ excl,
                  int* __restrict__ blocksums, int nn) {
    const int tid = threadIdx.x, lane = tid & 63, wid = tid >> 6;
    const int i0 = blockIdx.x * 1024 + tid * 4;
    int v0 = (i0 + 0 < nn) ? hist[i0 + 0] : 0;
    int v1 = (i0 + 1 < nn) ? hist[i0 + 1] : 0;
    int v2 = (i0 + 2 < nn) ? hist[i0 + 2] : 0;
    int v3 = (i0 + 3 < nn) ? hist[i0 + 3] : 0;
    const int s = v0 + v1 + v2 + v3;
    int incl = s;
    #pragma unroll
    for (int d = 1; d < 64; d <<= 1) {
        int t = __shfl_up(incl, d, 64);
        if (lane >= d) incl += t;
    }
    __shared__ int wt[4];
    if (lane == 63) wt[wid] = incl;
    __syncthreads();
    int wbase = 0;
    #pragma unroll
    for (int w = 0; w < 4; ++w) { int t = wt[w]; if (w < wid) wbase += t; }
    int total = wt[0] + wt[1] + wt[2] + wt[3];
    int e = wbase + (incl - s);
    if (i0 + 0 < nn) excl[i0 + 0] = e;  e += v0;
    if (i0 + 1 < nn) excl[i0 + 1] = e;  e += v1;
    if (i0 + 2 < nn) excl[i0 + 2] = e;  e += v2;
    if (i0 + 3 < nn) excl[i0 + 3] = e;
    if (tid == 0) blocksums[blockIdx.x] = total;
}

__global__ void scanB_kernel(int* __restrict__ blocksums, int* __restrict__ offsets,
                             int nb, int nn, int E) {
    const int lane = threadIdx.x;   // 64
    int v = (lane < nb) ? blocksums[lane] : 0;
    int incl = v;
    #pragma unroll
    for (int d = 1; d < 64; d <<= 1) {
        int t = __shfl_up(incl, d, 64);
        if (lane >= d) incl += t;
    }
    if (lane < nb) blocksums[lane] = incl - v;
    if (lane == 0) offsets[nn] = E;
}

__global__ __launch_bounds__(256)
void scanC_kernel(int* __restrict__ offsets, int* __restrict__ cursor,
                  const int* __restrict__ blocksums, int nn) {
    const int i0 = blockIdx.x * 1024 + threadIdx.x * 4;
    const int base = blocksums[blockIdx.x];
    #pragma unroll
    for (int j = 0; j < 4; ++j) {
        const int i = i0 + j;
        if (i < nn) { const int o = offsets[i] + base; offsets[i] = o; cursor[i] = o; }
    }
}

__global__ void fill_csr_kernel(const int* __restrict__ src, const int* __restrict__ dst,
                                int* __restrict__ cursor, int* __restrict__ csr, int E) {
    int i = blockIdx.x * blockDim.x + threadIdx.x;
    if (i < E) {
        int p = atomicAdd(&cursor[dst[i]], 1);
        csr[p] = src[i];
    }
}

// ---------------------------------------------------------------- aggregation (bf16)
// mean over incoming edges; C channels, C/8 threads per node (16B lanes)
template <int C>
__global__ __launch_bounds__(256)
void agg_kernel(const ushort_t* __restrict__ h, const int* __restrict__ offsets,
                const int* __restrict__ csr, ushort_t* __restrict__ out, int nn) {
    constexpr int TPN = C / 8;
    constexpr int NPB = 256 / TPN;
    const int node = blockIdx.x * NPB + (int)(threadIdx.x / TPN);
    const int lane = threadIdx.x % TPN;
    if (node >= nn) return;
    const int e0 = offsets[node], e1 = offsets[node + 1];
    float a0=0.f,a1=0.f,a2=0.f,a3=0.f,a4=0.f,a5=0.f,a6=0.f,a7=0.f;
    for (int e = e0; e < e1; ++e) {
        const int s = csr[e];
        const uint4 v = *(const uint4*)(h + (size_t)s * C + lane * 8);
        a0 += bflo(v.x); a1 += bfhi(v.x);
        a2 += bflo(v.y); a3 += bfhi(v.y);
        a4 += bflo(v.z); a5 += bfhi(v.z);
        a6 += bflo(v.w); a7 += bfhi(v.w);
    }
    const float inv = 1.0f / fmaxf((float)(e1 - e0), 1.0f);
    uint4 o;
    o.x = packbf(a0 * inv, a1 * inv);
    o.y = packbf(a2 * inv, a3 * inv);
    o.z = packbf(a4 * inv, a5 * inv);
    o.w = packbf(a6 * inv, a7 * inv);
    *(uint4*)(out + (size_t)node * C + lane * 8) = o;
}

// ---------------------------------------------------------------- MFMA dual GEMM
// C[M,256] = relu(A1 @ W1^T + A2 @ W2^T + bias), all bf16 in / fp32 acc / bf16 out.
// W row-major [256,K] bf16. 128x128 tile, 4 waves of 64x64, BK=64.
// LDS: [128 rows][8 chunks of 8 bf16], chunk swizzled by (row&7) -> <=2-way banks.
template <int K>
__global__ __launch_bounds__(256)
void gemm2_mfma(const ushort_t* __restrict__ A1, const ushort_t* __restrict__ A2,
                const ushort_t* __restrict__ W1, const ushort_t* __restrict__ W2,
                const float* __restrict__ bias, ushort_t* __restrict__ Cout, int M) {
    __shared__ ushort_t As[128 * 64];
    __shared__ ushort_t Bs[128 * 64];
    const int tid = threadIdx.x;
    const int row0 = blockIdx.x * 128, col0 = blockIdx.y * 128;
    const int wave = tid >> 6, lane = tid & 63;
    const int wm = (wave & 1) * 64, wn = (wave >> 1) * 64;
    const int l15 = lane & 15, quad = lane >> 4;

    f32x4 acc[4][4] = {};

    #pragma unroll
    for (int phase = 0; phase < 2; ++phase) {
        const ushort_t* __restrict__ A = phase ? A2 : A1;
        const ushort_t* __restrict__ W = phase ? W2 : W1;
        for (int kt = 0; kt < K; kt += 64) {
            __syncthreads();   // prior LDS reads complete
            #pragma unroll
            for (int p = 0; p < 4; ++p) {
                const int slot = p * 256 + tid;
                const int r = slot >> 3, c = slot & 7;
                const int cg = c ^ (r & 7);
                int ar = row0 + r; if (ar >= M) ar = M - 1;
                gld16(A + (size_t)ar * K + kt + cg * 8, &As[slot * 8]);
            }
            #pragma unroll
            for (int p = 0; p < 4; ++p) {
                const int slot = p * 256 + tid;
                const int r = slot >> 3, c = slot & 7;
                const int cg = c ^ (r & 7);
                gld16(W + (size_t)(col0 + r) * K + kt + cg * 8, &Bs[slot * 8]);
            }
            __syncthreads();   // staging visible (drains vmcnt)
            #pragma unroll
            for (int ks = 0; ks < 2; ++ks) {
                bf16x8 af[4], bfv[4];
                #pragma unroll
                for (int i = 0; i < 4; ++i) {
                    const int r = wm + i * 16 + l15;
                    const int cl = (ks * 4 + quad) ^ (r & 7);
                    af[i] = *(const bf16x8*)&As[r * 64 + cl * 8];
                }
                #pragma unroll
                for (int j = 0; j < 4; ++j) {
                    const int r = wn + j * 16 + l15;
                    const int cl = (ks * 4 + quad) ^ (r & 7);
                    bfv[j] = *(const bf16x8*)&Bs[r * 64 + cl * 8];
                }
                #pragma unroll
                for (int i = 0; i < 4; ++i)
                    #pragma unroll
                    for (int j = 0; j < 4; ++j)
                        acc[i][j] = __builtin_amdgcn_mfma_f32_16x16x32_bf16(
                            af[i], bfv[j], acc[i][j], 0, 0, 0);
            }
        }
    }

    // epilogue: C/D layout m = quad*4+reg, n = l15 per 16x16 subtile
    #pragma unroll
    for (int i = 0; i < 4; ++i) {
        const int mbase = row0 + wm + i * 16 + quad * 4;
        #pragma unroll
        for (int j = 0; j < 4; ++j) {
            const int n = col0 + wn + j * 16 + l15;
            const float b = bias[n];
            #pragma unroll
            for (int reg = 0; reg < 4; ++reg) {
                const int mr = mbase + reg;
                if (mr < M) {
                    const float v = fmaxf(acc[i][j][reg] + b, 0.f);
                    Cout[(size_t)mr * 256 + n] = f2bf(v);
                }
            }
        }
    }
}

// ---------------------------------------------------------------- pooling
__global__ __launch_bounds__(256)
void count_nodes_kernel(const int* __restrict__ batch, int* __restrict__ counts, int nn) {
    __shared__ int h[64];
    const int tid = threadIdx.x;
    if (tid < 64) h[tid] = 0;
    __syncthreads();
    const int i0 = blockIdx.x * 1024 + tid * 4;
    #pragma unroll
    for (int j = 0; j < 4; ++j) {
        const int i = i0 + j;
        if (i < nn) atomicAdd(&h[batch[i]], 1);
    }
    __syncthreads();
    if (tid < 64 && h[tid] != 0) atomicAdd(&counts[tid], h[tid]);
}

// batch sorted: per-block 64-node chunk, flush on graph change (bf16 input)
__global__ __launch_bounds__(256)
void pool_kernel(const ushort_t* __restrict__ h, const int* __restrict__ batch,
                 float* __restrict__ pooled, int nn) {
    const int c = threadIdx.x;          // 256 channels
    const int n0 = blockIdx.x * 64;
    const int n1 = min(n0 + 64, nn);
    if (n0 >= nn) return;
    float acc = 0.f;
    int cur = batch[n0];
    for (int n = n0; n < n1; ++n) {
        const int g = batch[n];
        if (g != cur) {
            atomicAdd(&pooled[cur * 256 + c], acc);
            acc = 0.f; cur = g;
        }
        acc += bflo((unsigned int)h[(size_t)n * 256 + c]);
    }
    atomicAdd(&pooled[cur * 256 + c], acc);
}

__global__ __launch_bounds__(128)
void mlp_kernel(const float* __restrict__ pooled, const int* __restrict__ counts,
                const float* __restrict__ lin1W, const float* __restrict__ lin1b,
                const float* __restrict__ lin2W, const float* __restrict__ lin2b,
                float* __restrict__ out) {
    __shared__ float g1[128];
    const int g = blockIdx.x;
    const int j = threadIdx.x;
    const float inv = 1.0f / fmaxf((float)counts[g], 1.0f);
    float acc = lin1b[j];
    #pragma unroll 4
    for (int k = 0; k < 256; ++k)
        acc = fmaf(pooled[g * 256 + k] * inv, lin1W[j * 256 + k], acc);
    g1[j] = fmaxf(acc, 0.f);
    __syncthreads();
    if (j < 10) {
        float o = lin2b[j];
        #pragma unroll 4
        for (int k = 0; k < 128; ++k)
            o = fmaf(g1[k], lin2W[j * 128 + k], o);
        out[g * 10 + j] = o;
    }
}

// ---------------------------------------------------------------- launcher
extern "C" void kernel_launch(void* const* d_in, const int* in_sizes, int n_in,
                              void* d_out, int out_size, void* d_ws, size_t ws_size,
                              hipStream_t stream) {
    const float* x     = (const float*)d_in[0];
    const int*   eidx  = (const int*)d_in[1];
    const int*   batch = (const int*)d_in[2];
    const float* W1l = (const float*)d_in[3];
    const float* b1  = (const float*)d_in[4];
    const float* W1r = (const float*)d_in[5];
    const float* W2l = (const float*)d_in[6];
    const float* b2  = (const float*)d_in[7];
    const float* W2r = (const float*)d_in[8];
    const float* W3l = (const float*)d_in[9];
    const float* b3  = (const float*)d_in[10];
    const float* W3r = (const float*)d_in[11];
    const float* lin1W = (const float*)d_in[12];
    const float* lin1b = (const float*)d_in[13];
    const float* lin2W = (const float*)d_in[14];
    const float* lin2b = (const float*)d_in[15];
    float* out = (float*)d_out;

    const int E  = in_sizes[1] / 2;
    const int NN = in_sizes[2];
    const int IN = 128;
    const int* src = eidx;
    const int* dst = eidx + E;

    // workspace layout (256B aligned chunks), bf16 activations
    char* ws = (char*)d_ws;
    size_t off = 0;
    auto alloc = [&](size_t bytes) { void* p = ws + off; off += (bytes + 255) / 256 * 256; return p; };
    ushort_t* xb  = (ushort_t*)alloc((size_t)NN * IN * 2);
    ushort_t* agg = (ushort_t*)alloc((size_t)NN * HID * 2);
    ushort_t* hA  = (ushort_t*)alloc((size_t)NN * HID * 2);
    ushort_t* hB  = (ushort_t*)alloc((size_t)NN * HID * 2);
    const int s1 = HID * IN, s2 = HID * HID;
    ushort_t* wb  = (ushort_t*)alloc((size_t)(2 * s1 + 4 * s2) * 2);
    int* offsets   = (int*)alloc((size_t)(NN + 1) * 4);
    int* cursor    = (int*)alloc((size_t)NN * 4);
    int* csr       = (int*)alloc((size_t)E * 4);
    int* blocksums = (int*)alloc(256);
    float* pooled  = (float*)alloc(64 * 256 * 4 + 256);   // + counts right after
    int* counts    = (int*)(pooled + 64 * 256);
    (void)ws_size; (void)n_in; (void)out_size;

    const ushort_t* W1lb = wb;
    const ushort_t* W1rb = wb + s1;
    const ushort_t* W2lb = wb + 2 * s1;
    const ushort_t* W2rb = wb + 2 * s1 + s2;
    const ushort_t* W3lb = wb + 2 * s1 + 2 * s2;
    const ushort_t* W3rb = wb + 2 * s1 + 3 * s2;

    const int TB = 256;
    const int egrid = (E + TB - 1) / TB;
    const int mgrid = (NN + 127) / 128;
    const int sgrid = (NN + 1023) / 1024;

    // --- conversions ---
    cvt_x_kernel<<<(NN * IN / 4 + TB - 1) / TB, TB, 0, stream>>>(x, xb, NN * IN);
    cvt_w_kernel<<<(2 * s1 + 4 * s2 + TB - 1) / TB, TB, 0, stream>>>(
        W1l, W1r, W2l, W2r, W3l, W3r, wb, s1, s2);

    // --- CSR build ---
    hipMemsetAsync(cursor, 0, (size_t)NN * 4, stream);
    count_deg_kernel<<<egrid, TB, 0, stream>>>(dst, cursor, E);
    scanA_kernel<<<sgrid, TB, 0, stream>>>(cursor, offsets, blocksums, NN);
    scanB_kernel<<<1, 64, 0, stream>>>(blocksums, offsets, sgrid, NN, E);
    scanC_kernel<<<sgrid, TB, 0, stream>>>(offsets, cursor, blocksums, NN);
    fill_csr_kernel<<<egrid, TB, 0, stream>>>(src, dst, cursor, csr, E);

    // --- layer 1 (K=128) ---
    agg_kernel<128><<<(NN + 15) / 16, TB, 0, stream>>>(xb, offsets, csr, agg, NN);
    gemm2_mfma<128><<<dim3(mgrid, 2), TB, 0, stream>>>(agg, xb, W1lb, W1rb, b1, hA, NN);
    // --- layer 2 ---
    agg_kernel<256><<<(NN + 7) / 8, TB, 0, stream>>>(hA, offsets, csr, agg, NN);
    gemm2_mfma<256><<<dim3(mgrid, 2), TB, 0, stream>>>(agg, hA, W2lb, W2rb, b2, hB, NN);
    // --- layer 3 ---
    agg_kernel<256><<<(NN + 7) / 8, TB, 0, stream>>>(hB, offsets, csr, agg, NN);
    gemm2_mfma<256><<<dim3(mgrid, 2), TB, 0, stream>>>(agg, hB, W3lb, W3rb, b3, hA, NN);

    // --- pool + MLP ---
    hipMemsetAsync(pooled, 0, 64 * 256 * 4 + 256, stream);
    count_nodes_kernel<<<sgrid, TB, 0, stream>>>(batch, counts, NN);
    pool_kernel<<<(NN + 63) / 64, TB, 0, stream>>>(hA, batch, pooled, NN);
    mlp_kernel<<<64, 128, 0, stream>>>(pooled, counts, lin1W, lin1b, lin2W, lin2b, out);
}

// Round 4
// 466.606 us; speedup vs baseline: 2.7100x; 1.0411x over previous
//
#include <hip/hip_runtime.h>
#include <hip/hip_bf16.h>

// GNNClassifier: 3x SAGEConv(mean) + ReLU -> global_mean_pool -> Linear+ReLU -> Linear
// N=50000 nodes, E=800000 edges, IN=128, HID=256, OUT=10, G=64 graphs.
//
// R4: attack agg latency (R3 top: 66us, VALUBusy 23%, ~2 loads in flight).
//  - agg: one wave per node, CL ch-lanes x EW edge-slots, edge loop unrolled x4
//    -> 8 outstanding 16B gathers/lane; __shfl_xor combine.
//  - tail fused: batch is sorted -> block g binary-searches its range,
//    LDS-reduces mean, runs MLP inline (drops memset/count/pool/mlp launches).
//  - bf16 MFMA GEMMs unchanged from R3.

#define HID 256
typedef unsigned short ushort_t;
typedef __bf16 bf16x8 __attribute__((ext_vector_type(8)));
typedef float  f32x4  __attribute__((ext_vector_type(4)));

__device__ __forceinline__ unsigned short f2bf(float f) {
    unsigned int u = __float_as_uint(f);
    unsigned int r = (u + 0x7fffu + ((u >> 16) & 1u)) >> 16;
    return (unsigned short)r;
}
__device__ __forceinline__ float bflo(unsigned int u) { return __uint_as_float(u << 16); }
__device__ __forceinline__ float bfhi(unsigned int u) { return __uint_as_float(u & 0xffff0000u); }
__device__ __forceinline__ unsigned int packbf(float a, float b) {
    return (unsigned int)f2bf(a) | ((unsigned int)f2bf(b) << 16);
}
__device__ __forceinline__ void gld16(const void* g, void* l) {
    __builtin_amdgcn_global_load_lds(
        (const __attribute__((address_space(1))) unsigned int*)g,
        (__attribute__((address_space(3))) unsigned int*)l, 16, 0, 0);
}
__device__ __forceinline__ void acc8(float* a, const uint4 v) {
    a[0] += bflo(v.x); a[1] += bfhi(v.x);
    a[2] += bflo(v.y); a[3] += bfhi(v.y);
    a[4] += bflo(v.z); a[5] += bfhi(v.z);
    a[6] += bflo(v.w); a[7] += bfhi(v.w);
}

// ---------------------------------------------------------------- conversions
__global__ __launch_bounds__(256)
void cvt_x_kernel(const float* __restrict__ x, ushort_t* __restrict__ xb, int n) {
    const int i = (blockIdx.x * 256 + threadIdx.x) * 4;
    if (i < n) {
        const float4 v = *(const float4*)(x + i);
        *(uint2*)(xb + i) = make_uint2(packbf(v.x, v.y), packbf(v.z, v.w));
    }
}

__global__ __launch_bounds__(256)
void cvt_w_kernel(const float* __restrict__ W1l, const float* __restrict__ W1r,
                  const float* __restrict__ W2l, const float* __restrict__ W2r,
                  const float* __restrict__ W3l, const float* __restrict__ W3r,
                  ushort_t* __restrict__ dst, int s1, int s2) {
    const int i = blockIdx.x * 256 + threadIdx.x;
    const int total = 2 * s1 + 4 * s2;
    if (i >= total) return;
    int off = i;
    const float* src;
    if (off < s1) src = W1l;
    else if ((off -= s1) < s1) src = W1r;
    else if ((off -= s1) < s2) src = W2l;
    else if ((off -= s2) < s2) src = W2r;
    else if ((off -= s2) < s2) src = W3l;
    else { off -= s2; src = W3r; }
    dst[i] = f2bf(src[off]);
}

// ---------------------------------------------------------------- CSR build
__global__ void count_deg_kernel(const int* __restrict__ dst, int* __restrict__ hist, int E) {
    int i = blockIdx.x * blockDim.x + threadIdx.x;
    if (i < E) atomicAdd(&hist[dst[i]], 1);
}

__global__ __launch_bounds__(256)
void scanA_kernel(const int* __restrict__ hist, int* __restrict__ excl,
                  int* __restrict__ blocksums, int nn) {
    const int tid = threadIdx.x, lane = tid & 63, wid = tid >> 6;
    const int i0 = blockIdx.x * 1024 + tid * 4;
    int v0 = (i0 + 0 < nn) ? hist[i0 + 0] : 0;
    int v1 = (i0 + 1 < nn) ? hist[i0 + 1] : 0;
    int v2 = (i0 + 2 < nn) ? hist[i0 + 2] : 0;
    int v3 = (i0 + 3 < nn) ? hist[i0 + 3] : 0;
    const int s = v0 + v1 + v2 + v3;
    int incl = s;
    #pragma unroll
    for (int d = 1; d < 64; d <<= 1) {
        int t = __shfl_up(incl, d, 64);
        if (lane >= d) incl += t;
    }
    __shared__ int wt[4];
    if (lane == 63) wt[wid] = incl;
    __syncthreads();
    int wbase = 0;
    #pragma unroll
    for (int w = 0; w < 4; ++w) { int t = wt[w]; if (w < wid) wbase += t; }
    int total = wt[0] + wt[1] + wt[2] + wt[3];
    int e = wbase + (incl - s);
    if (i0 + 0 < nn) excl[i0 + 0] = e;  e += v0;
    if (i0 + 1 < nn) excl[i0 + 1] = e;  e += v1;
    if (i0 + 2 < nn) excl[i0 + 2] = e;  e += v2;
    if (i0 + 3 < nn) excl[i0 + 3] = e;
    if (tid == 0) blocksums[blockIdx.x] = total;
}

__global__ void scanB_kernel(int* __restrict__ blocksums, int* __restrict__ offsets,
                             int nb, int nn, int E) {
    const int lane = threadIdx.x;   // 64
    int v = (lane < nb) ? blocksums[lane] : 0;
    int incl = v;
    #pragma unroll
    for (int d = 1; d < 64; d <<= 1) {
        int t = __shfl_up(incl, d, 64);
        if (lane >= d) incl += t;
    }
    if (lane < nb) blocksums[lane] = incl - v;
    if (lane == 0) offsets[nn] = E;
}

__global__ __launch_bounds__(256)
void scanC_kernel(int* __restrict__ offsets, int* __restrict__ cursor,
                  const int* __restrict__ blocksums, int nn) {
    const int i0 = blockIdx.x * 1024 + threadIdx.x * 4;
    const int base = blocksums[blockIdx.x];
    #pragma unroll
    for (int j = 0; j < 4; ++j) {
        const int i = i0 + j;
        if (i < nn) { const int o = offsets[i] + base; offsets[i] = o; cursor[i] = o; }
    }
}

__global__ void fill_csr_kernel(const int* __restrict__ src, const int* __restrict__ dst,
                                int* __restrict__ cursor, int* __restrict__ csr, int E) {
    int i = blockIdx.x * blockDim.x + threadIdx.x;
    if (i < E) {
        int p = atomicAdd(&cursor[dst[i]], 1);
        csr[p] = src[i];
    }
}

// ---------------------------------------------------------------- aggregation (bf16)
// one wave per node: CL channel-lanes (16B each) x EW edge-slots; edge loop
// unrolled x4 -> 8 outstanding gathers/lane; __shfl_xor combine across slots.
template <int C>
__global__ __launch_bounds__(256)
void agg_kernel(const ushort_t* __restrict__ h, const int* __restrict__ offsets,
                const int* __restrict__ csr, ushort_t* __restrict__ out, int nn) {
    constexpr int CL = C / 8;       // 16 (C=128) or 32 (C=256)
    constexpr int EW = 64 / CL;     // 4 or 2 edges per wave pass
    const int node = (blockIdx.x * 256 + threadIdx.x) >> 6;
    if (node >= nn) return;
    const int lane = threadIdx.x & 63;
    const int cl = lane & (CL - 1);
    const int eo = lane / CL;
    const int e0 = offsets[node], e1 = offsets[node + 1];
    float a[8] = {0.f, 0.f, 0.f, 0.f, 0.f, 0.f, 0.f, 0.f};
    int e = e0 + eo;
    for (; e + 3 * EW < e1; e += 4 * EW) {
        const int s0 = csr[e];
        const int s1 = csr[e + EW];
        const int s2 = csr[e + 2 * EW];
        const int s3 = csr[e + 3 * EW];
        const uint4 v0 = *(const uint4*)(h + (size_t)s0 * C + cl * 8);
        const uint4 v1 = *(const uint4*)(h + (size_t)s1 * C + cl * 8);
        const uint4 v2 = *(const uint4*)(h + (size_t)s2 * C + cl * 8);
        const uint4 v3 = *(const uint4*)(h + (size_t)s3 * C + cl * 8);
        acc8(a, v0); acc8(a, v1); acc8(a, v2); acc8(a, v3);
    }
    for (; e < e1; e += EW) {
        const int s0 = csr[e];
        const uint4 v0 = *(const uint4*)(h + (size_t)s0 * C + cl * 8);
        acc8(a, v0);
    }
    #pragma unroll
    for (int d = CL; d < 64; d <<= 1)
        #pragma unroll
        for (int r = 0; r < 8; ++r) a[r] += __shfl_xor(a[r], d, 64);
    if (eo == 0) {
        const float inv = 1.0f / fmaxf((float)(e1 - e0), 1.0f);
        uint4 o;
        o.x = packbf(a[0] * inv, a[1] * inv);
        o.y = packbf(a[2] * inv, a[3] * inv);
        o.z = packbf(a[4] * inv, a[5] * inv);
        o.w = packbf(a[6] * inv, a[7] * inv);
        *(uint4*)(out + (size_t)node * C + cl * 8) = o;
    }
}

// ---------------------------------------------------------------- MFMA dual GEMM
// C[M,256] = relu(A1 @ W1^T + A2 @ W2^T + bias), bf16 in / fp32 acc / bf16 out.
// 128x128 tile, 4 waves of 64x64, BK=64, global_load_lds w16, XOR-swizzled LDS.
template <int K>
__global__ __launch_bounds__(256)
void gemm2_mfma(const ushort_t* __restrict__ A1, const ushort_t* __restrict__ A2,
                const ushort_t* __restrict__ W1, const ushort_t* __restrict__ W2,
                const float* __restrict__ bias, ushort_t* __restrict__ Cout, int M) {
    __shared__ ushort_t As[128 * 64];
    __shared__ ushort_t Bs[128 * 64];
    const int tid = threadIdx.x;
    const int row0 = blockIdx.x * 128, col0 = blockIdx.y * 128;
    const int wave = tid >> 6, lane = tid & 63;
    const int wm = (wave & 1) * 64, wn = (wave >> 1) * 64;
    const int l15 = lane & 15, quad = lane >> 4;

    f32x4 acc[4][4] = {};

    #pragma unroll
    for (int phase = 0; phase < 2; ++phase) {
        const ushort_t* __restrict__ A = phase ? A2 : A1;
        const ushort_t* __restrict__ W = phase ? W2 : W1;
        for (int kt = 0; kt < K; kt += 64) {
            __syncthreads();
            #pragma unroll
            for (int p = 0; p < 4; ++p) {
                const int slot = p * 256 + tid;
                const int r = slot >> 3, c = slot & 7;
                const int cg = c ^ (r & 7);
                int ar = row0 + r; if (ar >= M) ar = M - 1;
                gld16(A + (size_t)ar * K + kt + cg * 8, &As[slot * 8]);
            }
            #pragma unroll
            for (int p = 0; p < 4; ++p) {
                const int slot = p * 256 + tid;
                const int r = slot >> 3, c = slot & 7;
                const int cg = c ^ (r & 7);
                gld16(W + (size_t)(col0 + r) * K + kt + cg * 8, &Bs[slot * 8]);
            }
            __syncthreads();
            #pragma unroll
            for (int ks = 0; ks < 2; ++ks) {
                bf16x8 af[4], bfv[4];
                #pragma unroll
                for (int i = 0; i < 4; ++i) {
                    const int r = wm + i * 16 + l15;
                    const int cl = (ks * 4 + quad) ^ (r & 7);
                    af[i] = *(const bf16x8*)&As[r * 64 + cl * 8];
                }
                #pragma unroll
                for (int j = 0; j < 4; ++j) {
                    const int r = wn + j * 16 + l15;
                    const int cl = (ks * 4 + quad) ^ (r & 7);
                    bfv[j] = *(const bf16x8*)&Bs[r * 64 + cl * 8];
                }
                #pragma unroll
                for (int i = 0; i < 4; ++i)
                    #pragma unroll
                    for (int j = 0; j < 4; ++j)
                        acc[i][j] = __builtin_amdgcn_mfma_f32_16x16x32_bf16(
                            af[i], bfv[j], acc[i][j], 0, 0, 0);
            }
        }
    }

    #pragma unroll
    for (int i = 0; i < 4; ++i) {
        const int mbase = row0 + wm + i * 16 + quad * 4;
        #pragma unroll
        for (int j = 0; j < 4; ++j) {
            const int n = col0 + wn + j * 16 + l15;
            const float b = bias[n];
            #pragma unroll
            for (int reg = 0; reg < 4; ++reg) {
                const int mr = mbase + reg;
                if (mr < M) {
                    const float v = fmaxf(acc[i][j][reg] + b, 0.f);
                    Cout[(size_t)mr * 256 + n] = f2bf(v);
                }
            }
        }
    }
}

// ---------------------------------------------------------------- fused pool+MLP
// batch sorted: block g binary-searches its node range, LDS-reduces mean, MLP inline.
__global__ __launch_bounds__(256)
void pool_mlp_kernel(const ushort_t* __restrict__ h, const int* __restrict__ batch, int nn,
                     const float* __restrict__ lin1W, const float* __restrict__ lin1b,
                     const float* __restrict__ lin2W, const float* __restrict__ lin2b,
                     float* __restrict__ out) {
    const int g = blockIdx.x;
    const int tid = threadIdx.x;
    int lo = 0, hi = nn;
    while (lo < hi) { int mid = (lo + hi) >> 1; if (batch[mid] < g) lo = mid + 1; else hi = mid; }
    const int s = lo;
    hi = nn;
    while (lo < hi) { int mid = (lo + hi) >> 1; if (batch[mid] < g + 1) lo = mid + 1; else hi = mid; }
    const int e = lo;

    const int cl = tid & 31, rg = tid >> 5;   // 32 ch-lanes x 8 row-groups
    float a[8] = {0.f, 0.f, 0.f, 0.f, 0.f, 0.f, 0.f, 0.f};
    for (int n = s + rg; n < e; n += 8) {
        const uint4 v = *(const uint4*)(h + (size_t)n * 256 + cl * 8);
        acc8(a, v);
    }
    __shared__ float red[8][256];
    #pragma unroll
    for (int r = 0; r < 8; ++r) red[rg][cl * 8 + r] = a[r];
    __syncthreads();
    __shared__ float meanv[256];
    float ssum = 0.f;
    #pragma unroll
    for (int r = 0; r < 8; ++r) ssum += red[r][tid];
    meanv[tid] = ssum / fmaxf((float)(e - s), 1.0f);
    __syncthreads();
    __shared__ float g1[128];
    if (tid < 128) {
        float acc = lin1b[tid];
        #pragma unroll 4
        for (int k = 0; k < 256; k += 4) {
            const float4 w = *(const float4*)(lin1W + tid * 256 + k);
            acc += meanv[k] * w.x + meanv[k + 1] * w.y + meanv[k + 2] * w.z + meanv[k + 3] * w.w;
        }
        g1[tid] = fmaxf(acc, 0.f);
    }
    __syncthreads();
    if (tid < 10) {
        float o = lin2b[tid];
        #pragma unroll 4
        for (int k = 0; k < 128; k += 4) {
            const float4 w = *(const float4*)(lin2W + tid * 128 + k);
            o += g1[k] * w.x + g1[k + 1] * w.y + g1[k + 2] * w.z + g1[k + 3] * w.w;
        }
        out[g * 10 + tid] = o;
    }
}

// ---------------------------------------------------------------- launcher
extern "C" void kernel_launch(void* const* d_in, const int* in_sizes, int n_in,
                              void* d_out, int out_size, void* d_ws, size_t ws_size,
                              hipStream_t stream) {
    const float* x     = (const float*)d_in[0];
    const int*   eidx  = (const int*)d_in[1];
    const int*   batch = (const int*)d_in[2];
    const float* W1l = (const float*)d_in[3];
    const float* b1  = (const float*)d_in[4];
    const float* W1r = (const float*)d_in[5];
    const float* W2l = (const float*)d_in[6];
    const float* b2  = (const float*)d_in[7];
    const float* W2r = (const float*)d_in[8];
    const float* W3l = (const float*)d_in[9];
    const float* b3  = (const float*)d_in[10];
    const float* W3r = (const float*)d_in[11];
    const float* lin1W = (const float*)d_in[12];
    const float* lin1b = (const float*)d_in[13];
    const float* lin2W = (const float*)d_in[14];
    const float* lin2b = (const float*)d_in[15];
    float* out = (float*)d_out;

    const int E  = in_sizes[1] / 2;
    const int NN = in_sizes[2];
    const int IN = 128;
    const int* src = eidx;
    const int* dst = eidx + E;

    char* ws = (char*)d_ws;
    size_t off = 0;
    auto alloc = [&](size_t bytes) { void* p = ws + off; off += (bytes + 255) / 256 * 256; return p; };
    ushort_t* xb  = (ushort_t*)alloc((size_t)NN * IN * 2);
    ushort_t* agg = (ushort_t*)alloc((size_t)NN * HID * 2);
    ushort_t* hA  = (ushort_t*)alloc((size_t)NN * HID * 2);
    ushort_t* hB  = (ushort_t*)alloc((size_t)NN * HID * 2);
    const int s1 = HID * IN, s2 = HID * HID;
    ushort_t* wb  = (ushort_t*)alloc((size_t)(2 * s1 + 4 * s2) * 2);
    int* offsets   = (int*)alloc((size_t)(NN + 1) * 4);
    int* cursor    = (int*)alloc((size_t)NN * 4);
    int* csr       = (int*)alloc((size_t)E * 4);
    int* blocksums = (int*)alloc(256);
    (void)ws_size; (void)n_in; (void)out_size;

    const ushort_t* W1lb = wb;
    const ushort_t* W1rb = wb + s1;
    const ushort_t* W2lb = wb + 2 * s1;
    const ushort_t* W2rb = wb + 2 * s1 + s2;
    const ushort_t* W3lb = wb + 2 * s1 + 2 * s2;
    const ushort_t* W3rb = wb + 2 * s1 + 3 * s2;

    const int TB = 256;
    const int egrid = (E + TB - 1) / TB;
    const int mgrid = (NN + 127) / 128;
    const int sgrid = (NN + 1023) / 1024;

    // --- conversions ---
    cvt_x_kernel<<<(NN * IN / 4 + TB - 1) / TB, TB, 0, stream>>>(x, xb, NN * IN);
    cvt_w_kernel<<<(2 * s1 + 4 * s2 + TB - 1) / TB, TB, 0, stream>>>(
        W1l, W1r, W2l, W2r, W3l, W3r, wb, s1, s2);

    // --- CSR build ---
    hipMemsetAsync(cursor, 0, (size_t)NN * 4, stream);
    count_deg_kernel<<<egrid, TB, 0, stream>>>(dst, cursor, E);
    scanA_kernel<<<sgrid, TB, 0, stream>>>(cursor, offsets, blocksums, NN);
    scanB_kernel<<<1, 64, 0, stream>>>(blocksums, offsets, sgrid, NN, E);
    scanC_kernel<<<sgrid, TB, 0, stream>>>(offsets, cursor, blocksums, NN);
    fill_csr_kernel<<<egrid, TB, 0, stream>>>(src, dst, cursor, csr, E);

    // --- layer 1 (K=128) ---
    agg_kernel<128><<<(NN + 3) / 4, TB, 0, stream>>>(xb, offsets, csr, agg, NN);
    gemm2_mfma<128><<<dim3(mgrid, 2), TB, 0, stream>>>(agg, xb, W1lb, W1rb, b1, hA, NN);
    // --- layer 2 ---
    agg_kernel<256><<<(NN + 3) / 4, TB, 0, stream>>>(hA, offsets, csr, agg, NN);
    gemm2_mfma<256><<<dim3(mgrid, 2), TB, 0, stream>>>(agg, hA, W2lb, W2rb, b2, hB, NN);
    // --- layer 3 ---
    agg_kernel<256><<<(NN + 3) / 4, TB, 0, stream>>>(hB, offsets, csr, agg, NN);
    gemm2_mfma<256><<<dim3(mgrid, 2), TB, 0, stream>>>(agg, hB, W3lb, W3rb, b3, hA, NN);

    // --- fused pool + MLP ---
    pool_mlp_kernel<<<64, TB, 0, stream>>>(hA, batch, NN, lin1W, lin1b, lin2W, lin2b, out);
}

// Round 5
// 455.773 us; speedup vs baseline: 2.7744x; 1.0238x over previous
//
#include <hip/hip_runtime.h>
#include <hip/hip_bf16.h>

// GNNClassifier: 3x SAGEConv(mean) + ReLU -> global_mean_pool -> Linear+ReLU -> Linear
// N=50000 nodes, E=800000 edges, IN=128, HID=256, OUT=10, G=64 graphs.
//
// R5: agg predicated+pipelined (no remainder loop; 4 gathers + 4 idx loads in
// flight, clamped idx + 0/1 fmac weights); cvt fused; scanB folded into scanC.

#define HID 256
typedef unsigned short ushort_t;
typedef __bf16 bf16x8 __attribute__((ext_vector_type(8)));
typedef float  f32x4  __attribute__((ext_vector_type(4)));

__device__ __forceinline__ unsigned short f2bf(float f) {
    unsigned int u = __float_as_uint(f);
    unsigned int r = (u + 0x7fffu + ((u >> 16) & 1u)) >> 16;
    return (unsigned short)r;
}
__device__ __forceinline__ float bflo(unsigned int u) { return __uint_as_float(u << 16); }
__device__ __forceinline__ float bfhi(unsigned int u) { return __uint_as_float(u & 0xffff0000u); }
__device__ __forceinline__ unsigned int packbf(float a, float b) {
    return (unsigned int)f2bf(a) | ((unsigned int)f2bf(b) << 16);
}
__device__ __forceinline__ void gld16(const void* g, void* l) {
    __builtin_amdgcn_global_load_lds(
        (const __attribute__((address_space(1))) unsigned int*)g,
        (__attribute__((address_space(3))) unsigned int*)l, 16, 0, 0);
}
__device__ __forceinline__ void fma8(float* a, float w, const uint4 v) {
    a[0] = fmaf(w, bflo(v.x), a[0]); a[1] = fmaf(w, bfhi(v.x), a[1]);
    a[2] = fmaf(w, bflo(v.y), a[2]); a[3] = fmaf(w, bfhi(v.y), a[3]);
    a[4] = fmaf(w, bflo(v.z), a[4]); a[5] = fmaf(w, bfhi(v.z), a[5]);
    a[6] = fmaf(w, bflo(v.w), a[6]); a[7] = fmaf(w, bfhi(v.w), a[7]);
}
__device__ __forceinline__ void acc8(float* a, const uint4 v) {
    a[0] += bflo(v.x); a[1] += bfhi(v.x);
    a[2] += bflo(v.y); a[3] += bfhi(v.y);
    a[4] += bflo(v.z); a[5] += bfhi(v.z);
    a[6] += bflo(v.w); a[7] += bfhi(v.w);
}
__device__ __forceinline__ int4 load4idx(const int* __restrict__ csr, int pbase, int e1m1) {
    int4 r;
    r.x = csr[min(pbase + 0, e1m1)];
    r.y = csr[min(pbase + 1, e1m1)];
    r.z = csr[min(pbase + 2, e1m1)];
    r.w = csr[min(pbase + 3, e1m1)];
    return r;
}

// ---------------------------------------------------------------- fused conversion
// threads [0, nx4): x float4 -> bf16x4 ; threads [nx4, nx4+wtotal): weight elems
__global__ __launch_bounds__(256)
void cvt_kernel(const float* __restrict__ x, ushort_t* __restrict__ xb, int nx4,
                const float* __restrict__ W1l, const float* __restrict__ W1r,
                const float* __restrict__ W2l, const float* __restrict__ W2r,
                const float* __restrict__ W3l, const float* __restrict__ W3r,
                ushort_t* __restrict__ wdst, int s1, int s2) {
    const int t = blockIdx.x * 256 + threadIdx.x;
    if (t < nx4) {
        const int i = t * 4;
        const float4 v = *(const float4*)(x + i);
        *(uint2*)(xb + i) = make_uint2(packbf(v.x, v.y), packbf(v.z, v.w));
        return;
    }
    int off = t - nx4;
    const int total = 2 * s1 + 4 * s2;
    if (off >= total) return;
    const int i = off;
    const float* src;
    if (off < s1) src = W1l;
    else if ((off -= s1) < s1) src = W1r;
    else if ((off -= s1) < s2) src = W2l;
    else if ((off -= s2) < s2) src = W2r;
    else if ((off -= s2) < s2) src = W3l;
    else { off -= s2; src = W3r; }
    wdst[i] = f2bf(src[off]);
}

// ---------------------------------------------------------------- CSR build
__global__ void count_deg_kernel(const int* __restrict__ dst, int* __restrict__ hist, int E) {
    int i = blockIdx.x * blockDim.x + threadIdx.x;
    if (i < E) atomicAdd(&hist[dst[i]], 1);
}

__global__ __launch_bounds__(256)
void scanA_kernel(const int* __restrict__ hist, int* __restrict__ excl,
                  int* __restrict__ blocksums, int nn) {
    const int tid = threadIdx.x, lane = tid & 63, wid = tid >> 6;
    const int i0 = blockIdx.x * 1024 + tid * 4;
    int v0 = (i0 + 0 < nn) ? hist[i0 + 0] : 0;
    int v1 = (i0 + 1 < nn) ? hist[i0 + 1] : 0;
    int v2 = (i0 + 2 < nn) ? hist[i0 + 2] : 0;
    int v3 = (i0 + 3 < nn) ? hist[i0 + 3] : 0;
    const int s = v0 + v1 + v2 + v3;
    int incl = s;
    #pragma unroll
    for (int d = 1; d < 64; d <<= 1) {
        int t = __shfl_up(incl, d, 64);
        if (lane >= d) incl += t;
    }
    __shared__ int wt[4];
    if (lane == 63) wt[wid] = incl;
    __syncthreads();
    int wbase = 0;
    #pragma unroll
    for (int w = 0; w < 4; ++w) { int t = wt[w]; if (w < wid) wbase += t; }
    int total = wt[0] + wt[1] + wt[2] + wt[3];
    int e = wbase + (incl - s);
    if (i0 + 0 < nn) excl[i0 + 0] = e;  e += v0;
    if (i0 + 1 < nn) excl[i0 + 1] = e;  e += v1;
    if (i0 + 2 < nn) excl[i0 + 2] = e;  e += v2;
    if (i0 + 3 < nn) excl[i0 + 3] = e;
    if (tid == 0) blocksums[blockIdx.x] = total;
}

// adds block-prefix of blocksums inline (replaces old scanB); inits cursor.
__global__ __launch_bounds__(256)
void scanC_kernel(int* __restrict__ offsets, int* __restrict__ cursor,
                  const int* __restrict__ blocksums, int nn, int E) {
    int base = 0;
    const int nb = (int)blockIdx.x;
    for (int b = 0; b < nb; ++b) base += blocksums[b];   // <=48 uniform L2 reads
    const int i0 = blockIdx.x * 1024 + threadIdx.x * 4;
    #pragma unroll
    for (int j = 0; j < 4; ++j) {
        const int i = i0 + j;
        if (i < nn) { const int o = offsets[i] + base; offsets[i] = o; cursor[i] = o; }
    }
    if (blockIdx.x == gridDim.x - 1 && threadIdx.x == 0) offsets[nn] = E;
}

__global__ void fill_csr_kernel(const int* __restrict__ src, const int* __restrict__ dst,
                                int* __restrict__ cursor, int* __restrict__ csr, int E) {
    int i = blockIdx.x * blockDim.x + threadIdx.x;
    if (i < E) {
        int p = atomicAdd(&cursor[dst[i]], 1);
        csr[p] = src[i];
    }
}

// ---------------------------------------------------------------- aggregation (bf16)
// one wave/node; CL ch-lanes x EW edge-slots; every round: 4 contiguous edges
// per slot, predicated (clamped idx + 0/1 fmac weight), next-round idx prefetch.
template <int C>
__global__ __launch_bounds__(256)
void agg_kernel(const ushort_t* __restrict__ h, const int* __restrict__ offsets,
                const int* __restrict__ csr, ushort_t* __restrict__ out, int nn, int E) {
    constexpr int CL = C / 8;       // 16 (C=128) or 32 (C=256)
    constexpr int EW = 64 / CL;     // 4 or 2 edge slots
    constexpr int RPE = 4 * EW;     // edges per wave-round (16 or 8)
    const int node = (blockIdx.x * 256 + threadIdx.x) >> 6;
    if (node >= nn) return;
    const int lane = threadIdx.x & 63;
    const int cl = lane & (CL - 1);
    const int eo = lane / CL;
    const int e0 = offsets[node], e1 = offsets[node + 1];
    const int deg = e1 - e0;
    const int rounds = (deg + RPE - 1) / RPE;   // wave-uniform
    const int e1m1 = max(e1 - 1, 0);
    float a[8] = {0.f, 0.f, 0.f, 0.f, 0.f, 0.f, 0.f, 0.f};
    int pb = e0 + eo * 4;
    if (rounds > 0) {
        int4 idx = load4idx(csr, pb, e1m1);
        for (int r2 = 0; r2 < rounds; ++r2) {
            const int4 cur = idx;
            const int pcur = pb;
            pb += RPE;
            if (r2 + 1 < rounds) idx = load4idx(csr, pb, e1m1);
            const uint4 v0 = *(const uint4*)(h + (size_t)cur.x * C + cl * 8);
            const uint4 v1 = *(const uint4*)(h + (size_t)cur.y * C + cl * 8);
            const uint4 v2 = *(const uint4*)(h + (size_t)cur.z * C + cl * 8);
            const uint4 v3 = *(const uint4*)(h + (size_t)cur.w * C + cl * 8);
            fma8(a, (pcur + 0 < e1) ? 1.f : 0.f, v0);
            fma8(a, (pcur + 1 < e1) ? 1.f : 0.f, v1);
            fma8(a, (pcur + 2 < e1) ? 1.f : 0.f, v2);
            fma8(a, (pcur + 3 < e1) ? 1.f : 0.f, v3);
        }
    }
    #pragma unroll
    for (int d = CL; d < 64; d <<= 1)
        #pragma unroll
        for (int r = 0; r < 8; ++r) a[r] += __shfl_xor(a[r], d, 64);
    if (eo == 0) {
        const float inv = 1.0f / fmaxf((float)deg, 1.0f);
        uint4 o;
        o.x = packbf(a[0] * inv, a[1] * inv);
        o.y = packbf(a[2] * inv, a[3] * inv);
        o.z = packbf(a[4] * inv, a[5] * inv);
        o.w = packbf(a[6] * inv, a[7] * inv);
        *(uint4*)(out + (size_t)node * C + cl * 8) = o;
    }
}

// ---------------------------------------------------------------- MFMA dual GEMM
template <int K>
__global__ __launch_bounds__(256)
void gemm2_mfma(const ushort_t* __restrict__ A1, const ushort_t* __restrict__ A2,
                const ushort_t* __restrict__ W1, const ushort_t* __restrict__ W2,
                const float* __restrict__ bias, ushort_t* __restrict__ Cout, int M) {
    __shared__ ushort_t As[128 * 64];
    __shared__ ushort_t Bs[128 * 64];
    const int tid = threadIdx.x;
    const int row0 = blockIdx.x * 128, col0 = blockIdx.y * 128;
    const int wave = tid >> 6, lane = tid & 63;
    const int wm = (wave & 1) * 64, wn = (wave >> 1) * 64;
    const int l15 = lane & 15, quad = lane >> 4;

    f32x4 acc[4][4] = {};

    #pragma unroll
    for (int phase = 0; phase < 2; ++phase) {
        const ushort_t* __restrict__ A = phase ? A2 : A1;
        const ushort_t* __restrict__ W = phase ? W2 : W1;
        for (int kt = 0; kt < K; kt += 64) {
            __syncthreads();
            #pragma unroll
            for (int p = 0; p < 4; ++p) {
                const int slot = p * 256 + tid;
                const int r = slot >> 3, c = slot & 7;
                const int cg = c ^ (r & 7);
                int ar = row0 + r; if (ar >= M) ar = M - 1;
                gld16(A + (size_t)ar * K + kt + cg * 8, &As[slot * 8]);
            }
            #pragma unroll
            for (int p = 0; p < 4; ++p) {
                const int slot = p * 256 + tid;
                const int r = slot >> 3, c = slot & 7;
                const int cg = c ^ (r & 7);
                gld16(W + (size_t)(col0 + r) * K + kt + cg * 8, &Bs[slot * 8]);
            }
            __syncthreads();
            #pragma unroll
            for (int ks = 0; ks < 2; ++ks) {
                bf16x8 af[4], bfv[4];
                #pragma unroll
                for (int i = 0; i < 4; ++i) {
                    const int r = wm + i * 16 + l15;
                    const int cl = (ks * 4 + quad) ^ (r & 7);
                    af[i] = *(const bf16x8*)&As[r * 64 + cl * 8];
                }
                #pragma unroll
                for (int j = 0; j < 4; ++j) {
                    const int r = wn + j * 16 + l15;
                    const int cl = (ks * 4 + quad) ^ (r & 7);
                    bfv[j] = *(const bf16x8*)&Bs[r * 64 + cl * 8];
                }
                #pragma unroll
                for (int i = 0; i < 4; ++i)
                    #pragma unroll
                    for (int j = 0; j < 4; ++j)
                        acc[i][j] = __builtin_amdgcn_mfma_f32_16x16x32_bf16(
                            af[i], bfv[j], acc[i][j], 0, 0, 0);
            }
        }
    }

    #pragma unroll
    for (int i = 0; i < 4; ++i) {
        const int mbase = row0 + wm + i * 16 + quad * 4;
        #pragma unroll
        for (int j = 0; j < 4; ++j) {
            const int n = col0 + wn + j * 16 + l15;
            const float b = bias[n];
            #pragma unroll
            for (int reg = 0; reg < 4; ++reg) {
                const int mr = mbase + reg;
                if (mr < M) {
                    const float v = fmaxf(acc[i][j][reg] + b, 0.f);
                    Cout[(size_t)mr * 256 + n] = f2bf(v);
                }
            }
        }
    }
}

// ---------------------------------------------------------------- fused pool+MLP
__global__ __launch_bounds__(256)
void pool_mlp_kernel(const ushort_t* __restrict__ h, const int* __restrict__ batch, int nn,
                     const float* __restrict__ lin1W, const float* __restrict__ lin1b,
                     const float* __restrict__ lin2W, const float* __restrict__ lin2b,
                     float* __restrict__ out) {
    const int g = blockIdx.x;
    const int tid = threadIdx.x;
    int lo = 0, hi = nn;
    while (lo < hi) { int mid = (lo + hi) >> 1; if (batch[mid] < g) lo = mid + 1; else hi = mid; }
    const int s = lo;
    hi = nn;
    while (lo < hi) { int mid = (lo + hi) >> 1; if (batch[mid] < g + 1) lo = mid + 1; else hi = mid; }
    const int e = lo;

    const int cl = tid & 31, rg = tid >> 5;
    float a[8] = {0.f, 0.f, 0.f, 0.f, 0.f, 0.f, 0.f, 0.f};
    for (int n = s + rg; n < e; n += 8) {
        const uint4 v = *(const uint4*)(h + (size_t)n * 256 + cl * 8);
        acc8(a, v);
    }
    __shared__ float red[8][256];
    #pragma unroll
    for (int r = 0; r < 8; ++r) red[rg][cl * 8 + r] = a[r];
    __syncthreads();
    __shared__ float meanv[256];
    float ssum = 0.f;
    #pragma unroll
    for (int r = 0; r < 8; ++r) ssum += red[r][tid];
    meanv[tid] = ssum / fmaxf((float)(e - s), 1.0f);
    __syncthreads();
    __shared__ float g1[128];
    if (tid < 128) {
        float acc = lin1b[tid];
        #pragma unroll 4
        for (int k = 0; k < 256; k += 4) {
            const float4 w = *(const float4*)(lin1W + tid * 256 + k);
            acc += meanv[k] * w.x + meanv[k + 1] * w.y + meanv[k + 2] * w.z + meanv[k + 3] * w.w;
        }
        g1[tid] = fmaxf(acc, 0.f);
    }
    __syncthreads();
    if (tid < 10) {
        float o = lin2b[tid];
        #pragma unroll 4
        for (int k = 0; k < 128; k += 4) {
            const float4 w = *(const float4*)(lin2W + tid * 128 + k);
            o += g1[k] * w.x + g1[k + 1] * w.y + g1[k + 2] * w.z + g1[k + 3] * w.w;
        }
        out[g * 10 + tid] = o;
    }
}

// ---------------------------------------------------------------- launcher
extern "C" void kernel_launch(void* const* d_in, const int* in_sizes, int n_in,
                              void* d_out, int out_size, void* d_ws, size_t ws_size,
                              hipStream_t stream) {
    const float* x     = (const float*)d_in[0];
    const int*   eidx  = (const int*)d_in[1];
    const int*   batch = (const int*)d_in[2];
    const float* W1l = (const float*)d_in[3];
    const float* b1  = (const float*)d_in[4];
    const float* W1r = (const float*)d_in[5];
    const float* W2l = (const float*)d_in[6];
    const float* b2  = (const float*)d_in[7];
    const float* W2r = (const float*)d_in[8];
    const float* W3l = (const float*)d_in[9];
    const float* b3  = (const float*)d_in[10];
    const float* W3r = (const float*)d_in[11];
    const float* lin1W = (const float*)d_in[12];
    const float* lin1b = (const float*)d_in[13];
    const float* lin2W = (const float*)d_in[14];
    const float* lin2b = (const float*)d_in[15];
    float* out = (float*)d_out;

    const int E  = in_sizes[1] / 2;
    const int NN = in_sizes[2];
    const int IN = 128;
    const int* src = eidx;
    const int* dst = eidx + E;

    char* ws = (char*)d_ws;
    size_t off = 0;
    auto alloc = [&](size_t bytes) { void* p = ws + off; off += (bytes + 255) / 256 * 256; return p; };
    ushort_t* xb  = (ushort_t*)alloc((size_t)NN * IN * 2);
    ushort_t* agg = (ushort_t*)alloc((size_t)NN * HID * 2);
    ushort_t* hA  = (ushort_t*)alloc((size_t)NN * HID * 2);
    ushort_t* hB  = (ushort_t*)alloc((size_t)NN * HID * 2);
    const int s1 = HID * IN, s2 = HID * HID;
    ushort_t* wb  = (ushort_t*)alloc((size_t)(2 * s1 + 4 * s2) * 2);
    int* offsets   = (int*)alloc((size_t)(NN + 1) * 4);
    int* cursor    = (int*)alloc((size_t)NN * 4);
    int* csr       = (int*)alloc((size_t)E * 4);
    int* blocksums = (int*)alloc(256);
    (void)ws_size; (void)n_in; (void)out_size;

    const ushort_t* W1lb = wb;
    const ushort_t* W1rb = wb + s1;
    const ushort_t* W2lb = wb + 2 * s1;
    const ushort_t* W2rb = wb + 2 * s1 + s2;
    const ushort_t* W3lb = wb + 2 * s1 + 2 * s2;
    const ushort_t* W3rb = wb + 2 * s1 + 3 * s2;

    const int TB = 256;
    const int egrid = (E + TB - 1) / TB;
    const int mgrid = (NN + 127) / 128;
    const int sgrid = (NN + 1023) / 1024;

    // --- fused conversion ---
    const int nx4 = NN * IN / 4;
    const int wtotal = 2 * s1 + 4 * s2;
    cvt_kernel<<<(nx4 + wtotal + TB - 1) / TB, TB, 0, stream>>>(
        x, xb, nx4, W1l, W1r, W2l, W2r, W3l, W3r, wb, s1, s2);

    // --- CSR build ---
    hipMemsetAsync(cursor, 0, (size_t)NN * 4, stream);
    count_deg_kernel<<<egrid, TB, 0, stream>>>(dst, cursor, E);
    scanA_kernel<<<sgrid, TB, 0, stream>>>(cursor, offsets, blocksums, NN);
    scanC_kernel<<<sgrid, TB, 0, stream>>>(offsets, cursor, blocksums, NN, E);
    fill_csr_kernel<<<egrid, TB, 0, stream>>>(src, dst, cursor, csr, E);

    // --- layer 1 (K=128) ---
    agg_kernel<128><<<(NN + 3) / 4, TB, 0, stream>>>(xb, offsets, csr, agg, NN, E);
    gemm2_mfma<128><<<dim3(mgrid, 2), TB, 0, stream>>>(agg, xb, W1lb, W1rb, b1, hA, NN);
    // --- layer 2 ---
    agg_kernel<256><<<(NN + 3) / 4, TB, 0, stream>>>(hA, offsets, csr, agg, NN, E);
    gemm2_mfma<256><<<dim3(mgrid, 2), TB, 0, stream>>>(agg, hA, W2lb, W2rb, b2, hB, NN);
    // --- layer 3 ---
    agg_kernel<256><<<(NN + 3) / 4, TB, 0, stream>>>(hB, offsets, csr, agg, NN, E);
    gemm2_mfma<256><<<dim3(mgrid, 2), TB, 0, stream>>>(agg, hB, W3lb, W3rb, b3, hA, NN);

    // --- fused pool + MLP ---
    pool_mlp_kernel<<<64, TB, 0, stream>>>(hA, batch, NN, lin1W, lin1b, lin2W, lin2b, out);
}